// Round 9
// baseline (396.323 us; speedup 1.0000x reference)
//
#include <hip/hip_runtime.h>

typedef __attribute__((ext_vector_type(4))) float   floatx4;
typedef __attribute__((ext_vector_type(8))) __bf16  bf16x8;
typedef unsigned short ushort_t;
typedef __attribute__((ext_vector_type(8))) ushort_t ushortx8;

typedef const unsigned int __attribute__((address_space(1)))* gptr_t;
typedef unsigned int __attribute__((address_space(3)))* lptr_t;

#define NIMG 32
#define H    112
#define W    112
#define CIN  128
#define COUT 256
#define HW   12544      // H*W, = 49*256 so every 256-row tile stays in one image

#define BM 256
#define BN 256
#define BK 64
#define NT 18           // K = 3*3*128 = 1152 = 18*64

// ---------- fp32 -> bf16 (round-to-nearest-even) ----------
__device__ __forceinline__ ushort_t f32_to_bf16(float f) {
    unsigned u = __float_as_uint(f);
    unsigned r = 0x7fffu + ((u >> 16) & 1u);
    return (ushort_t)((u + r) >> 16);
}

// pack 8 floats -> bf16x8, zeroed when invalid
__device__ __forceinline__ ushortx8 cvt_sel(floatx4 a, floatx4 b, bool v) {
    ushortx8 o;
#pragma unroll
    for (int j = 0; j < 4; ++j) {
        o[j]     = v ? f32_to_bf16(a[j]) : (ushort_t)0;
        o[4 + j] = v ? f32_to_bf16(b[j]) : (ushort_t)0;
    }
    return o;
}

// ---------- Prepass: kernel (3,3,128,256) fp32 HWIO -> bf16 [kh][kw][oc][ic] ----------
__global__ __launch_bounds__(256) void wtrans(const float* __restrict__ k,
                                              ushort_t* __restrict__ wt) {
    int t    = blockIdx.x * 256 + threadIdx.x;
    int ic   = t & 127;
    int oc   = (t >> 7) & 255;
    int khkw = t >> 15;
    wt[t] = f32_to_bf16(k[((size_t)(khkw * CIN + ic)) * COUT + oc]);
}

// ---------- K-tile offsets ----------
__device__ __forceinline__ int boffK(int t) {
    int tap = t >> 1;
    return tap * (COUT * CIN) + (t & 1) * 64;
}

// ---------- Main: 256x256 8-phase implicit-GEMM bf16 MFMA conv, fused A-convert ----------
// Base = round-8 PASSING kernel. Single structural change: A staged from the raw
// fp32 input via reg-staging (global fp32 loads -> cvt+zero-select -> ds_write),
// eliminating the pad prepass. B path (global_load_lds from wt) unchanged.
// Per-tile ledger (per wave): q0-pre issue A01(t+1):4 -> q1-tail vmcnt(0)
// [drains A01 + already-old B(t+1)], cvt+write01, issue A23(t+1):4 ->
// q2-pre STAGE_B(t+2,0):2 -> q2-tail vmcnt(2) [leaves B(t+2,0), drains A23],
// cvt+write23 -> q3-pre STAGE_B(t+2,1):2 -> q3-tail lgkmcnt(0) + barrier.
// B prefetch depth across barriers preserved; A-regs peak 16 VGPR.
// Padding: per-slice 9-bit validity mask (tap -> in-bounds); invalid lanes load
// the always-valid center address and select 0 at cvt.
// LDS layout + XOR swizzle byte-identical to the DMA version (A source offset
// pre-swizzled via lc; read-side cOff XOR unchanged).

__global__ __launch_bounds__(512, 2) void conv_mfma8(const float* __restrict__ in,
                                                     const ushort_t* __restrict__ wt,
                                                     const float* __restrict__ bias,
                                                     float* __restrict__ out) {
    __shared__ __align__(16) ushort_t lds[65536];   // 128 KiB

    const int tid  = threadIdx.x;
    const int wid  = tid >> 6;
    const int lane = tid & 63;
    const int wm   = wid >> 2;       // 0..1 : 128-row band
    const int wn   = wid & 3;        // 0..3 : 64-col band
    const int bid  = blockIdx.x;
    const int bm   = (bid & 7) * 196 + (bid >> 3);   // XCD swizzle, 1568 % 8 == 0

    // ---- staging geometry ----
    const int trow = tid >> 3;                // 0..63 : row within a 64-row slice
    const int lc   = (tid & 7) ^ (trow & 7);  // pre-swizzled 16B-chunk (8 channels)

    // A: fp32 element offsets + per-slice 9-tap validity bitmask
    int offA[4];
    int vbits[4];
    const ushort_t* srcB[4];
#pragma unroll
    for (int i = 0; i < 4; ++i) {
        int m  = bm * BM + i * 64 + trow;
        int n  = m / HW;
        int r  = m % HW;
        int oh = r / W;
        int ow = r % W;
        offA[i] = ((n * H + oh) * W + ow) * CIN + lc * 8;
        int vb = 0;
#pragma unroll
        for (int tap = 0; tap < 9; ++tap) {
            int kh = tap / 3, kw = tap - 3 * (tap / 3);
            if ((unsigned)(oh + kh - 1) < (unsigned)H && (unsigned)(ow + kw - 1) < (unsigned)W)
                vb |= (1 << tap);
        }
        vbits[i] = vb;
        srcB[i] = wt + (size_t)(i * 64 + trow) * CIN + lc * 8;
    }
    const int dstSlot = wid * 512;

#define STAGE_B(tile, half)                                                                         \
    { int _o = boffK(tile); int _b = ((tile) & 1) * 32768 + 16384 + (half) * 8192 + dstSlot;        \
      __builtin_amdgcn_global_load_lds((gptr_t)(srcB[(half)*2+0] + _o), (lptr_t)&lds[_b       ], 16, 0, 0); \
      __builtin_amdgcn_global_load_lds((gptr_t)(srcB[(half)*2+1] + _o), (lptr_t)&lds[_b + 4096], 16, 0, 0); }

// issue fp32 loads for A slice s of tile tt (tap kh,kw ; offF precomputed)
#define LOAD_A(s, offF, tapi)                                                                       \
    { bool _v = (vbits[s] >> (tapi)) & 1;                                                           \
      const float* _p = in + (ptrdiff_t)(offA[s] + (_v ? (offF) : 0));                              \
      fa0[s] = *reinterpret_cast<const floatx4*>(_p);                                               \
      fa1[s] = *reinterpret_cast<const floatx4*>(_p + 4); }
#define WRITE_A(s, bufn, tapi)                                                                      \
    { bool _v = (vbits[s] >> (tapi)) & 1;                                                           \
      *reinterpret_cast<ushortx8*>(&lds[(bufn) + (s) * 4096 + tid * 8]) = cvt_sel(fa0[s], fa1[s], _v); }

    // ---- read-side constants (ushort elems; row = 64 elems = 128 B) ----
    const int aBase = wm * 8192 + (lane & 15) * 64;
    const int bBase = 16384 + (wn >> 1) * 8192 + ((wn & 1) * 64 + (lane & 15)) * 64;
    int cOff[2];
#pragma unroll
    for (int ks = 0; ks < 2; ++ks)
        cOff[ks] = ((ks * 4 + (lane >> 4)) ^ (lane & 7)) * 8;

    floatx4 acc[8][4];
#pragma unroll
    for (int i = 0; i < 8; ++i)
#pragma unroll
        for (int j = 0; j < 4; ++j) acc[i][j] = (floatx4)0.0f;

    floatx4 fa0[4], fa1[4];

    // ---- prologue: A(0) two batches (tap 0: kh=0,kw=0), B(0), B(1) ----
    {
        const int offF0 = ((0 - 1) * W + (0 - 1)) * CIN;   // tap 0, ic-half 0
        LOAD_A(0, offF0, 0); LOAD_A(1, offF0, 0);
        asm volatile("s_waitcnt vmcnt(0)" ::: "memory");
        WRITE_A(0, 0, 0); WRITE_A(1, 0, 0);
        LOAD_A(2, offF0, 0); LOAD_A(3, offF0, 0);
        STAGE_B(0, 0); STAGE_B(0, 1);
        STAGE_B(1, 0); STAGE_B(1, 1);
        asm volatile("s_waitcnt vmcnt(8)" ::: "memory");   // drain A23, keep B(0)+B(1)
        WRITE_A(2, 0, 0); WRITE_A(3, 0, 0);
        asm volatile("s_waitcnt vmcnt(4)" ::: "memory");   // drain B(0), keep B(1)
        asm volatile("s_waitcnt lgkmcnt(0)" ::: "memory");
        __builtin_amdgcn_s_barrier();
    }

    // ---- main loop ----
    for (int t = 0; t < NT; ++t) {
        const int bufb = (t & 1) * 32768;
        const int bufn = ((t + 1) & 1) * 32768;
        // next-tile A tap (fp32 source, zero-based padding offset)
        const int tap1  = (t + 1) >> 1;
        const int kh1   = tap1 / 3;
        const int kw1   = tap1 - 3 * kh1;
        const int offF1 = ((kh1 - 1) * W + (kw1 - 1)) * CIN + ((t + 1) & 1) * 64;
        bf16x8 bfr[4][2];
#pragma unroll
        for (int q = 0; q < 4; ++q) {
            bf16x8 af[2][2];
#pragma unroll
            for (int rfl = 0; rfl < 2; ++rfl)
#pragma unroll
                for (int ks = 0; ks < 2; ++ks)
                    af[rfl][ks] = *reinterpret_cast<const bf16x8*>(&lds[bufb + aBase + (2 * q + rfl) * 1024 + cOff[ks]]);
            if (q == 0) {
#pragma unroll
                for (int cf = 0; cf < 2; ++cf)      // cf0/1 pre-barrier; cf2/3 deferred
#pragma unroll
                    for (int ks = 0; ks < 2; ++ks)
                        bfr[cf][ks] = *reinterpret_cast<const bf16x8*>(&lds[bufb + bBase + cf * 1024 + cOff[ks]]);
            }
            if (q == 0 && t + 1 < NT) { LOAD_A(0, offF1, tap1); LOAD_A(1, offF1, tap1); }
            if (q == 2 && t + 2 < NT) STAGE_B(t + 2, 0);
            if (q == 3 && t + 2 < NT) STAGE_B(t + 2, 1);
            __builtin_amdgcn_s_barrier();
            __builtin_amdgcn_s_setprio(1);
            if (q == 0) {
                // first half: cf0/1 MFMAs while b2/b3 reads issue mid-cluster
#pragma unroll
                for (int rfl = 0; rfl < 2; ++rfl)
#pragma unroll
                    for (int cf = 0; cf < 2; ++cf)
#pragma unroll
                        for (int ks = 0; ks < 2; ++ks)
                            acc[rfl][cf] = __builtin_amdgcn_mfma_f32_16x16x32_bf16(
                                af[rfl][ks], bfr[cf][ks], acc[rfl][cf], 0, 0, 0);
#pragma unroll
                for (int cf = 2; cf < 4; ++cf)      // deferred B reads (smooths q0 burst)
#pragma unroll
                    for (int ks = 0; ks < 2; ++ks)
                        bfr[cf][ks] = *reinterpret_cast<const bf16x8*>(&lds[bufb + bBase + cf * 1024 + cOff[ks]]);
#pragma unroll
                for (int rfl = 0; rfl < 2; ++rfl)
#pragma unroll
                    for (int cf = 2; cf < 4; ++cf)
#pragma unroll
                        for (int ks = 0; ks < 2; ++ks)
                            acc[rfl][cf] = __builtin_amdgcn_mfma_f32_16x16x32_bf16(
                                af[rfl][ks], bfr[cf][ks], acc[rfl][cf], 0, 0, 0);
            } else {
#pragma unroll
                for (int rfl = 0; rfl < 2; ++rfl)
#pragma unroll
                    for (int cf = 0; cf < 4; ++cf)
#pragma unroll
                        for (int ks = 0; ks < 2; ++ks)
                            acc[2 * q + rfl][cf] = __builtin_amdgcn_mfma_f32_16x16x32_bf16(
                                af[rfl][ks], bfr[cf][ks], acc[2 * q + rfl][cf], 0, 0, 0);
            }
            __builtin_amdgcn_s_setprio(0);
            if (q == 1 && t + 1 < NT) {
                asm volatile("s_waitcnt vmcnt(0)" ::: "memory");   // A01 + old B(t+1)
                WRITE_A(0, bufn, tap1); WRITE_A(1, bufn, tap1);
                LOAD_A(2, offF1, tap1); LOAD_A(3, offF1, tap1);
            }
            if (q == 2 && t + 1 < NT) {
                if (t < NT - 2) { asm volatile("s_waitcnt vmcnt(2)" ::: "memory"); }  // keep B(t+2,0)
                else            { asm volatile("s_waitcnt vmcnt(0)" ::: "memory"); }
                WRITE_A(2, bufn, tap1); WRITE_A(3, bufn, tap1);
            }
            if (q == 3) { asm volatile("s_waitcnt lgkmcnt(0)" ::: "memory"); }  // ds_write visibility
            __builtin_amdgcn_s_barrier();
        }
    }

    // ---- epilogue: C/D map col=lane&15, row=(lane>>4)*4+reg ----
    const int col0 = wn * 64 + (lane & 15);
    const int row0 = bm * BM + wm * 128 + (lane >> 4) * 4;
    float bv[4];
#pragma unroll
    for (int cf = 0; cf < 4; ++cf) bv[cf] = bias[col0 + cf * 16];
#pragma unroll
    for (int rf = 0; rf < 8; ++rf)
#pragma unroll
        for (int cf = 0; cf < 4; ++cf)
#pragma unroll
            for (int r = 0; r < 4; ++r)
                out[(size_t)(row0 + rf * 16 + r) * COUT + col0 + cf * 16] = acc[rf][cf][r] + bv[cf];
#undef STAGE_B
#undef LOAD_A
#undef WRITE_A
}

extern "C" void kernel_launch(void* const* d_in, const int* in_sizes, int n_in,
                              void* d_out, int out_size, void* d_ws, size_t ws_size,
                              hipStream_t stream) {
    const float* input = (const float*)d_in[0];
    const float* kern  = (const float*)d_in[1];
    const float* bias  = (const float*)d_in[2];
    float* out         = (float*)d_out;

    ushort_t* wt = (ushort_t*)d_ws;                           // 589,824 B

    wtrans<<<1152, 256, 0, stream>>>(kern, wt);
    conv_mfma8<<<1568, 512, 0, stream>>>(input, wt, bias, out);
}

// Round 10
// 352.572 us; speedup vs baseline: 1.1241x; 1.1241x over previous
//
#include <hip/hip_runtime.h>

typedef __attribute__((ext_vector_type(4))) float   floatx4;
typedef __attribute__((ext_vector_type(8))) __bf16  bf16x8;
typedef unsigned short ushort_t;
typedef __attribute__((ext_vector_type(8))) ushort_t ushortx8;

typedef const unsigned int __attribute__((address_space(1)))* gptr_t;
typedef unsigned int __attribute__((address_space(3)))* lptr_t;

#define NIMG 32
#define H    112
#define W    112
#define CIN  128
#define COUT 256
#define HP   114
#define WP   114
#define HW   12544      // H*W, = 49*256 so every 256-row tile stays in one image

#define BM 256
#define BN 256
#define BK 64
#define NT 18           // K = 3*3*128 = 1152 = 18*64

#define PREPAD_BLOCKS 12996   // 32*114*114*8 / 256  (32B per thread)
#define WTRANS_BLOCKS 1152    // 3*3*256*128 / 256

// ---------- fp32 -> bf16 (round-to-nearest-even) ----------
__device__ __forceinline__ ushort_t f32_to_bf16(float f) {
    unsigned u = __float_as_uint(f);
    unsigned r = 0x7fffu + ((u >> 16) & 1u);
    return (ushort_t)((u + r) >> 16);
}

// ---------- Fused prepass (r8-verified, unchanged) ----------
__global__ __launch_bounds__(256) void prepass_fused(const float* __restrict__ in,
                                                     const float* __restrict__ k,
                                                     ushort_t* __restrict__ pad,
                                                     ushort_t* __restrict__ wt) {
    int bid = blockIdx.x;
    if (bid < PREPAD_BLOCKS) {
        int u    = bid * 256 + threadIdx.x;
        int ic16 = u & 7;
        int sp   = u >> 3;
        int iw   = sp % WP;
        int sp2  = sp / WP;
        int ih   = sp2 % HP;
        int n    = sp2 / HP;
        ushortx8 v0, v1;
        if (ih >= 1 && ih <= H && iw >= 1 && iw <= W) {
            const float* src = in + ((size_t)((n * H + (ih - 1)) * W + (iw - 1))) * CIN + ic16 * 16;
            floatx4 a = *reinterpret_cast<const floatx4*>(src);
            floatx4 b = *reinterpret_cast<const floatx4*>(src + 4);
            floatx4 c = *reinterpret_cast<const floatx4*>(src + 8);
            floatx4 d = *reinterpret_cast<const floatx4*>(src + 12);
#pragma unroll
            for (int j = 0; j < 4; ++j) {
                v0[j] = f32_to_bf16(a[j]); v0[4 + j] = f32_to_bf16(b[j]);
                v1[j] = f32_to_bf16(c[j]); v1[4 + j] = f32_to_bf16(d[j]);
            }
        } else {
#pragma unroll
            for (int j = 0; j < 8; ++j) { v0[j] = 0; v1[j] = 0; }
        }
        ushortx8* dst = reinterpret_cast<ushortx8*>(pad) + ((size_t)sp * 16 + ic16 * 2);
        dst[0] = v0;
        dst[1] = v1;
    } else {
        int t    = (bid - PREPAD_BLOCKS) * 256 + threadIdx.x;
        int ic   = t & 127;
        int oc   = (t >> 7) & 255;
        int khkw = t >> 15;
        wt[t] = f32_to_bf16(k[((size_t)(khkw * CIN + ic)) * COUT + oc]);
    }
}

// ---------- K-tile global offsets ----------
__device__ __forceinline__ int aoffK(int t) {
    int tap = t >> 1;
    return ((tap / 3) * WP + (tap % 3)) * CIN + (t & 1) * 64;
}
__device__ __forceinline__ int boffK(int t) {
    int tap = t >> 1;
    return tap * (COUT * CIN) + (t & 1) * 64;
}

// ---------- Main: 256x256 8-phase, SINGLE-buffered LDS (64 KiB -> 2 blocks/CU) ----------
// Same tile/phase/MFMA/read structure as the r8 PASSING kernel; LDS halved by
// exploiting region lifetimes:
//   A chunk q (rows 32q..32q+32 of each 128-half) is read ONLY in phase q ->
//   stage chunk q of tile t+1 in phase q+1 (after the barrier retiring its reads);
//   chunk 3 of tile t is staged at q0 of t (region freed at q3 of t-1).
//   B is fully in regs after q0 (incl. deferred cf2/3) -> stage B(t+1) at q1/q2.
// Issues per wave: q0:1(Ac3 of t), q1:3(Ac0',B0',B1'), q2:3(Ac1',B2',B3'), q3:1(Ac2').
// Counted waits (FIFO-audited, incl. t=0/NT-2/NT-1):
//   q1-end vmcnt(4|1), q2-end vmcnt(6|0), q3-end vmcnt(1). Never 0 in steady state.
// Staging primitives: verified-envelope ONLY (full exec, uniform 16B gload_lds,
// wave-uniform dest + lane*16B, pre-swizzled per-lane global source lc^(row&7)).

__global__ __launch_bounds__(512, 2) void conv_mfma8(const ushort_t* __restrict__ pad,
                                                     const ushort_t* __restrict__ wt,
                                                     const float* __restrict__ bias,
                                                     float* __restrict__ out) {
    __shared__ __align__(16) ushort_t lds[32768];   // 64 KiB: A[256][64] @0, B[256][64] @16384

    const int tid  = threadIdx.x;
    const int wid  = tid >> 6;
    const int lane = tid & 63;
    const int wm   = wid >> 2;       // 0..1 : 128-row band
    const int wn   = wid & 3;        // 0..3 : 64-col band
    const int bid  = blockIdx.x;
    const int bm   = (bid & 7) * 196 + (bid >> 3);   // XCD swizzle, 1568 % 8 == 0

    // ---- A-chunk staging geometry ----
    // chunk q region = rows {32q..32q+32} U {128+32q..128+32q+32}; thread covers
    // row = 128*(tid>=256) + 32q + rb, rb=(tid&255)>>3; 16B slot tid&7.
    const int rb   = (tid & 255) >> 3;
    const int half = tid >> 8;
    const int lc   = (tid & 7) ^ (rb & 7);   // pre-swizzled logical chunk (row&7 == rb&7)

    const ushort_t* srcAc[4];
#pragma unroll
    for (int q = 0; q < 4; ++q) {
        int m  = bm * BM + half * 128 + q * 32 + rb;
        int n  = m / HW;
        int r  = m % HW;
        int oh = r / W;
        int ow = r % W;
        srcAc[q] = pad + ((size_t)((n * HP + oh) * WP + ow)) * CIN + lc * 8;
    }
    const ushort_t* srcB[4];
#pragma unroll
    for (int i = 0; i < 4; ++i)
        srcB[i] = wt + (size_t)(i * 64 + ((tid >> 3) & 63)) * CIN
                     + (((tid & 7) ^ ((tid >> 3) & 7)) * 8);

    // wave-uniform A-chunk dest base: (wid>>2)*8192 + (wid&3)*512 (+ q*2048)
    const int awBase   = (wid >> 2) * 8192 + (wid & 3) * 512;
    const int dstSlotB = wid * 512;

#define STAGE_AC(q_, oA)                                                                            \
    __builtin_amdgcn_global_load_lds((gptr_t)(srcAc[q_] + (oA)),                                    \
                                     (lptr_t)&lds[(q_) * 2048 + awBase], 16, 0, 0);
#define STAGE_B1(j_, oB)                                                                            \
    __builtin_amdgcn_global_load_lds((gptr_t)(srcB[j_] + (oB)),                                     \
                                     (lptr_t)&lds[16384 + (j_) * 4096 + dstSlotB], 16, 0, 0);

    // ---- read-side constants (identical addressing to r8, minus buffer parity) ----
    const int aBase = wm * 8192 + (lane & 15) * 64;
    const int bBase = 16384 + (wn >> 1) * 8192 + ((wn & 1) * 64 + (lane & 15)) * 64;
    int cOff[2];
#pragma unroll
    for (int ks = 0; ks < 2; ++ks)
        cOff[ks] = ((ks * 4 + (lane >> 4)) ^ (lane & 7)) * 8;

    floatx4 acc[8][4];
#pragma unroll
    for (int i = 0; i < 8; ++i)
#pragma unroll
        for (int j = 0; j < 4; ++j) acc[i][j] = (floatx4)0.0f;

    // ---- prologue: A(0) chunks 0-2 + B(0) slices 0-3; full drain (once) ----
    {
        const int oA0 = aoffK(0);
        const int oB0 = boffK(0);
        STAGE_AC(0, oA0); STAGE_AC(1, oA0); STAGE_AC(2, oA0);
        STAGE_B1(0, oB0); STAGE_B1(1, oB0); STAGE_B1(2, oB0); STAGE_B1(3, oB0);
    }
    asm volatile("s_waitcnt vmcnt(0)" ::: "memory");
    __builtin_amdgcn_s_barrier();

    // ---- main loop ----
    for (int t = 0; t < NT; ++t) {
        const int oAc = aoffK(t);        // current tile (chunk-3 stage)
        const int oAn = aoffK(t + 1);    // guarded uses
        const int oBn = boffK(t + 1);
        bf16x8 bfr[4][2];
#pragma unroll
        for (int q = 0; q < 4; ++q) {
            bf16x8 af[2][2];
#pragma unroll
            for (int rfl = 0; rfl < 2; ++rfl)
#pragma unroll
                for (int ks = 0; ks < 2; ++ks)
                    af[rfl][ks] = *reinterpret_cast<const bf16x8*>(&lds[aBase + (2 * q + rfl) * 1024 + cOff[ks]]);
            if (q == 0) {
#pragma unroll
                for (int cf = 0; cf < 2; ++cf)      // cf0/1 pre-barrier; cf2/3 deferred
#pragma unroll
                    for (int ks = 0; ks < 2; ++ks)
                        bfr[cf][ks] = *reinterpret_cast<const bf16x8*>(&lds[bBase + cf * 1024 + cOff[ks]]);
            }
            // staging issues (after the barrier that retired the region's reads)
            if (q == 0) { STAGE_AC(3, oAc); }
            if (q == 1 && t + 1 < NT) { STAGE_AC(0, oAn); STAGE_B1(0, oBn); STAGE_B1(1, oBn); }
            if (q == 2 && t + 1 < NT) { STAGE_AC(1, oAn); STAGE_B1(2, oBn); STAGE_B1(3, oBn); }
            if (q == 3 && t + 1 < NT) { STAGE_AC(2, oAn); }
            __builtin_amdgcn_s_barrier();
            __builtin_amdgcn_s_setprio(1);
            if (q == 0) {
#pragma unroll
                for (int rfl = 0; rfl < 2; ++rfl)
#pragma unroll
                    for (int cf = 0; cf < 2; ++cf)
#pragma unroll
                        for (int ks = 0; ks < 2; ++ks)
                            acc[rfl][cf] = __builtin_amdgcn_mfma_f32_16x16x32_bf16(
                                af[rfl][ks], bfr[cf][ks], acc[rfl][cf], 0, 0, 0);
#pragma unroll
                for (int cf = 2; cf < 4; ++cf)      // deferred B reads (q0-burst smoothing)
#pragma unroll
                    for (int ks = 0; ks < 2; ++ks)
                        bfr[cf][ks] = *reinterpret_cast<const bf16x8*>(&lds[bBase + cf * 1024 + cOff[ks]]);
#pragma unroll
                for (int rfl = 0; rfl < 2; ++rfl)
#pragma unroll
                    for (int cf = 2; cf < 4; ++cf)
#pragma unroll
                        for (int ks = 0; ks < 2; ++ks)
                            acc[rfl][cf] = __builtin_amdgcn_mfma_f32_16x16x32_bf16(
                                af[rfl][ks], bfr[cf][ks], acc[rfl][cf], 0, 0, 0);
            } else {
#pragma unroll
                for (int rfl = 0; rfl < 2; ++rfl)
#pragma unroll
                    for (int cf = 0; cf < 4; ++cf)
#pragma unroll
                        for (int ks = 0; ks < 2; ++ks)
                            acc[2 * q + rfl][cf] = __builtin_amdgcn_mfma_f32_16x16x32_bf16(
                                af[rfl][ks], bfr[cf][ks], acc[2 * q + rfl][cf], 0, 0, 0);
            }
            __builtin_amdgcn_s_setprio(0);
            // counted waits (FIFO ledger; see header comment)
            if (q == 1) {
                if (t < NT - 1) { asm volatile("s_waitcnt vmcnt(4)" ::: "memory"); }
                else            { asm volatile("s_waitcnt vmcnt(1)" ::: "memory"); }
            }
            if (q == 2) {
                if (t < NT - 1) { asm volatile("s_waitcnt vmcnt(6)" ::: "memory"); }
                else            { asm volatile("s_waitcnt vmcnt(0)" ::: "memory"); }
            }
            if (q == 3) { asm volatile("s_waitcnt vmcnt(1)" ::: "memory"); }
            __builtin_amdgcn_s_barrier();
        }
    }

    // ---- epilogue: C/D map col=lane&15, row=(lane>>4)*4+reg ----
    const int col0 = wn * 64 + (lane & 15);
    const int row0 = bm * BM + wm * 128 + (lane >> 4) * 4;
    float bv[4];
#pragma unroll
    for (int cf = 0; cf < 4; ++cf) bv[cf] = bias[col0 + cf * 16];
#pragma unroll
    for (int rf = 0; rf < 8; ++rf)
#pragma unroll
        for (int cf = 0; cf < 4; ++cf)
#pragma unroll
            for (int r = 0; r < 4; ++r)
                out[(size_t)(row0 + rf * 16 + r) * COUT + col0 + cf * 16] = acc[rf][cf][r] + bv[cf];
#undef STAGE_AC
#undef STAGE_B1
}

extern "C" void kernel_launch(void* const* d_in, const int* in_sizes, int n_in,
                              void* d_out, int out_size, void* d_ws, size_t ws_size,
                              hipStream_t stream) {
    const float* input = (const float*)d_in[0];
    const float* kern  = (const float*)d_in[1];
    const float* bias  = (const float*)d_in[2];
    float* out         = (float*)d_out;

    ushort_t* pad = (ushort_t*)d_ws;                          // 106,463,232 B
    ushort_t* wt  = pad + (size_t)NIMG * HP * WP * CIN;       // + 589,824 B

    prepass_fused<<<PREPAD_BLOCKS + WTRANS_BLOCKS, 256, 0, stream>>>(input, kern, pad, wt);
    conv_mfma8<<<1568, 512, 0, stream>>>(pad, wt, bias, out); // 1568 = 401408/256, %8==0
}